// Round 4
// baseline (125.960 us; speedup 1.0000x reference)
//
#include <hip/hip_runtime.h>

#define NQ 11
#define NL 3
#define S  2048
#define NB 8
#define NA 96
#define NF 64
#define PADW 100
#define WPB 4                  // waves (nodes) per block
#define PPB (NA / WPB)         // 24 circuit blocks per batch
#define NBLK (NB * NA / WPB)   // 192 blocks total
#define MAGIC 0x13572468u

typedef float v2f __attribute__((ext_vector_type(2)));

__device__ __forceinline__ float sigmoidf_(float x) { return 1.0f / (1.0f + expf(-x)); }

// uniform broadcast from a given lane (SGPR path, no DS traffic)
__device__ __forceinline__ float rl_(float v, int srclane) {
    return __builtin_bit_cast(float, __builtin_amdgcn_readlane(__builtin_bit_cast(int, v), srclane));
}

// lane-xor shuffle: DPP for masks 1,2,8; ds_swizzle for 4,16; bpermute path for 32
template<int M> __device__ __forceinline__ float sxf(float x) {
    if constexpr (M == 1)
        return __builtin_bit_cast(float, __builtin_amdgcn_mov_dpp(__builtin_bit_cast(int, x), 0xB1, 0xF, 0xF, true));
    else if constexpr (M == 2)
        return __builtin_bit_cast(float, __builtin_amdgcn_mov_dpp(__builtin_bit_cast(int, x), 0x4E, 0xF, 0xF, true));
    else if constexpr (M == 8)
        return __builtin_bit_cast(float, __builtin_amdgcn_mov_dpp(__builtin_bit_cast(int, x), 0x128, 0xF, 0xF, true));
    else if constexpr (M == 4)
        return __builtin_bit_cast(float, __builtin_amdgcn_ds_swizzle(__builtin_bit_cast(int, x), 0x101F));
    else if constexpr (M == 16)
        return __builtin_bit_cast(float, __builtin_amdgcn_ds_swizzle(__builtin_bit_cast(int, x), 0x401F));
    else
        return __shfl_xor(x, 32, 64);
}
template<int M> __device__ __forceinline__ v2f sxv(v2f w) {
    v2f r; r.x = sxf<M>(w.x); r.y = sxf<M>(w.y); return r;
}

// ---- gate primitives on the packed statevector w[16] (state = ((2j+c)<<6)|lane) ----
// rotation, qubit = lane bit Q (Q<6)
template<int Q> __device__ __forceinline__ void rot_lane(v2f* w, float g00, float g01,
                                                         float g10, float g11, int lane) {
    const int bit  = (lane >> Q) & 1;
    const float c1 = bit ? g11 : g00;   // own
    const float c0 = bit ? g10 : g01;   // partner
#pragma unroll
    for (int j = 0; j < 16; ++j) {
        v2f pw = sxv<(1 << Q)>(w[j]);
        w[j] = c1 * w[j] + c0 * pw;     // pk_mul + pk_fma
    }
}
// rotation, qubit = component bit (state bit 6)
__device__ __forceinline__ void rot_comp(v2f* w, float g00, float g01, float g10, float g11) {
    v2f ca; ca.x = g00; ca.y = g11;
    v2f cb; cb.x = g01; cb.y = g10;
#pragma unroll
    for (int j = 0; j < 16; ++j) {
        v2f sw; sw.x = w[j].y; sw.y = w[j].x;
        w[j] = ca * w[j] + cb * sw;
    }
}
// rotation, qubit = j bit B (state bit 7+B)
template<int B> __device__ __forceinline__ void rot_reg(v2f* w, float g00, float g01,
                                                        float g10, float g11) {
#pragma unroll
    for (int t = 0; t < 8; ++t) {
        const int j0 = ((t >> B) << (B + 1)) | (t & ((1 << B) - 1));
        const int j1 = j0 | (1 << B);
        v2f a0 = w[j0], a1 = w[j1];
        w[j0] = g00 * a0 + g01 * a1;
        w[j1] = g10 * a0 + g11 * a1;
    }
}
// ent: ctrl lane bit Q, target lane bit Q+1 (Q<5)
template<int Q> __device__ __forceinline__ void ent_lane(v2f* w, float p, int lane) {
    const float pact = p * (float)((lane >> Q) & 1);
#pragma unroll
    for (int j = 0; j < 16; ++j) {
        v2f pw = sxv<(1 << (Q + 1))>(w[j]);
        w[j] = w[j] + pact * (pw - w[j]);
    }
}
// ent q=5: ctrl lane bit 5, target = component bit
__device__ __forceinline__ void ent_5(v2f* w, float p, int lane) {
    const float pact = p * (float)((lane >> 5) & 1);
#pragma unroll
    for (int j = 0; j < 16; ++j) {
        v2f sw; sw.x = w[j].y; sw.y = w[j].x;
        w[j] = w[j] + pact * (sw - w[j]);
    }
}
// ent q=6: ctrl = component bit (y), target = j bit 0
__device__ __forceinline__ void ent_6(v2f* w, float p) {
#pragma unroll
    for (int t = 0; t < 8; ++t) {
        const int j0 = 2 * t, j1 = 2 * t + 1;
        const float d = w[j1].y - w[j0].y;
        w[j0].y = fmaf(p, d, w[j0].y);
        w[j1].y = fmaf(-p, d, w[j1].y);
    }
}
// ent q=7+B: ctrl = j bit B, target = j bit B+1 (B=0,1,2)
template<int B> __device__ __forceinline__ void ent_reg(v2f* w, float p) {
#pragma unroll
    for (int t = 0; t < 4; ++t) {
        const int j0 = ((t >> B) << (B + 2)) | (1 << B) | (t & ((1 << B) - 1));
        const int j1 = j0 | (1 << (B + 1));
        v2f d = w[j1] - w[j0];
        w[j0] = w[j0] + p * d;
        w[j1] = w[j1] - p * d;
    }
}

__global__ __launch_bounds__(256) void fused_kernel(
    const float* __restrict__ nf,     // [NB*NA, NF]
    const float* __restrict__ W1,     // [64,100]
    const float* __restrict__ b1,     // [64]
    const float* __restrict__ W2,     // [11,64]
    const float* __restrict__ b2,     // [11]
    const float* __restrict__ rot,    // [NL,NQ,3]
    const float* __restrict__ ent,    // [NL,NQ-1]
    const float* __restrict__ msg,    // [NL,NQ,3]
    const float* __restrict__ pool_w, // [11]
    const float* __restrict__ Wo1, const float* __restrict__ bo1,
    const float* __restrict__ Wo2, const float* __restrict__ bo2,
    const float* __restrict__ Wo3, const float* __restrict__ bo3,
    float* __restrict__ Rpart,        // [NBLK, S]
    unsigned* __restrict__ flags,     // [NBLK]
    float* __restrict__ out)          // [NB,64]
{
    __shared__ float W1s[64 * 65];    // stride-65 pad: 2-way bank alias (free)
    __shared__ float xs[WPB][64];
    __shared__ float psum[WPB][S];
    __shared__ float Theta[NQ];
    __shared__ float red[3][WPB];
    __shared__ float rm_sh, im_sh;
    __shared__ float h1[256];
    __shared__ float h2[128];

    const int tid  = threadIdx.x;
    const int lane = tid & 63;
    const int wave = tid >> 6;
    const int blk  = blockIdx.x;
    const int bb   = blk / PPB;       // batch
    const int pb   = blk % PPB;       // partial index within batch
    const int node = blk * WPB + wave;
    const int a    = node % NA;

    // ---- stage W1[:,0:64] into padded LDS + node features ----
    {
        const int r  = tid >> 2;
        const int c0 = (tid & 3) << 4;
        const float4* src = reinterpret_cast<const float4*>(W1 + r * PADW + c0);
        float* dst = &W1s[r * 65 + c0];
#pragma unroll
        for (int j = 0; j < 4; ++j) {
            const float4 vv = src[j];
            dst[4 * j + 0] = vv.x; dst[4 * j + 1] = vv.y;
            dst[4 * j + 2] = vv.z; dst[4 * j + 3] = vv.w;
        }
        xs[wave][lane] = nf[blk * WPB * NF + tid];
    }
    __syncthreads();

    // ---- h = relu(x @ W1[:, :64]^T + b1) ----
    float h = b1[lane];
    {
        const float* wrow = &W1s[lane * 65];
        const float* xv   = xs[wave];
#pragma unroll
        for (int k = 0; k < 64; ++k) h = fmaf(wrow[k], xv[k], h);
    }
    h = fmaxf(h, 0.0f);

    // ---- f[q] = tanh(b2[q] + h @ W2[q,:]) via wave butterfly; lane q keeps it ----
    float fscal = 0.0f;
#pragma unroll
    for (int q = 0; q < NQ; ++q) {
        float t = h * W2[q * 64 + lane];
#pragma unroll
        for (int off = 32; off >= 1; off >>= 1) t += __shfl_xor(t, off, 64);
        if (lane == q) fscal = tanhf(t + b2[q]);
    }

    // ---- lane g<33 computes gate g's 2x2 matrix; lane e<30 computes ent p ----
    const int qidx = lane < 11 ? lane : (lane < 22 ? lane - 11 : (lane < 33 ? lane - 22 : 0));
    const float fg = __shfl(fscal, qidx, 64);
    float m00 = 0.f, m01 = 0.f, m10 = 0.f, m11 = 0.f;
    if (lane < NL * NQ) {
        const float* r = rot + lane * 3;
        const float hx = 0.5f * r[0] * fg;
        const float hy = 0.5f * r[1] * fg;
        const float hz = 0.5f * r[2] * fg;
        const float cx = cosf(hx), sx = sinf(hx);
        const float cy = cosf(hy), sy = sinf(hy);
        const float cz = cosf(hz), sz = sinf(hz);
        m00 = cx * cy * cz; m01 = -sx * sy * sz;
        m10 = sx * sy * cz; m11 = cx * cy * sz;
    }
    float pent = 0.0f;
    if (lane < NL * (NQ - 1)) pent = sigmoidf_(ent[lane]);

    // ---- packed register statevector ----
    v2f w[16];
#pragma unroll
    for (int j = 0; j < 16; ++j) { w[j].x = 0.0f; w[j].y = 0.0f; }
    if (lane == 0) w[0].x = 1.0f;

#define GC(G) const int gi = gb + (G); \
    const float g00 = rl_(m00, gi), g01 = rl_(m01, gi), g10 = rl_(m10, gi), g11 = rl_(m11, gi)
#define ROTL(Q) { GC(Q); rot_lane<Q>(w, g00, g01, g10, g11, lane); }
#define ROTR(B) { GC((B) + 7); rot_reg<B>(w, g00, g01, g10, g11); }
#define ENTL(Q) { const float p = rl_(pent, eb + (Q)); ent_lane<Q>(w, p, lane); }

    for (int l = 0; l < NL; ++l) {
        const int gb = l * NQ;
        const int eb = l * (NQ - 1);
        ROTL(0) ROTL(1) ROTL(2) ROTL(3) ROTL(4) ROTL(5)
        { GC(6); rot_comp(w, g00, g01, g10, g11); }
        ROTR(0) ROTR(1) ROTR(2) ROTR(3)
        ENTL(0) ENTL(1) ENTL(2) ENTL(3) ENTL(4)
        { const float p = rl_(pent, eb + 5); ent_5(w, p, lane); }
        { const float p = rl_(pent, eb + 6); ent_6(w, p); }
        { const float p = rl_(pent, eb + 7); ent_reg<0>(w, p); }
        { const float p = rl_(pent, eb + 8); ent_reg<1>(w, p); }
        { const float p = rl_(pent, eb + 9); ent_reg<2>(w, p); }
    }

    // ---- weighted write into LDS, block reduction, partial store ----
    const float wgt = sigmoidf_(pool_w[a % NQ]);
#pragma unroll
    for (int j = 0; j < 16; ++j) {
        psum[wave][((2 * j + 0) << 6) | lane] = wgt * w[j].x;
        psum[wave][((2 * j + 1) << 6) | lane] = wgt * w[j].y;
    }
    __syncthreads();
    {
        float* Rb = Rpart + (size_t)blk * S;
        for (int s = tid; s < S; s += 256) {
            const float sum = psum[0][s] + psum[1][s] + psum[2][s] + psum[3][s];
            Rb[s] = sum;
            psum[0][s] = sum;          // keep own partial in LDS for the pool path
        }
    }
    __syncthreads();
    if (tid == 0) {
        __threadfence();               // release all partial stores device-wide
        __hip_atomic_store(&flags[blk], MAGIC, __ATOMIC_RELEASE, __HIP_MEMORY_SCOPE_AGENT);
    }

    if (pb != 0) return;

    // ================= designated pool block for batch bb =================
    if (tid < NQ) {
        float t = 0.0f;
        for (int l = 0; l < NL; ++l)
#pragma unroll
            for (int c = 0; c < 3; ++c) t += msg[(l * NQ + tid) * 3 + c];
        Theta[tid] = t;
    }
    if (tid < PPB - 1) {               // spin on the 23 sibling flags
        const unsigned* fp = flags + bb * PPB + 1 + tid;
        while (__hip_atomic_load(fp, __ATOMIC_RELAXED, __HIP_MEMORY_SCOPE_AGENT) != MAGIC)
            __builtin_amdgcn_s_sleep(2);
    }
    __syncthreads();
    __threadfence();                   // acquire: invalidate caches before reading partials

    float psq = 0.0f, pc = 0.0f, ps = 0.0f;
    {
        const float* Pb = Rpart + (size_t)bb * PPB * S;
        for (int s = tid; s < S; s += 256) {
            float R = psum[0][s];
#pragma unroll
            for (int j = 1; j < PPB; ++j) R += Pb[(size_t)j * S + s];
            float phi = 0.0f;
#pragma unroll
            for (int q = 0; q < NQ; ++q)
                if ((s >> q) & 1) phi += Theta[q];
            psq += R * R;
            pc  += R * cosf(phi);
            ps  += R * sinf(phi);
        }
    }
#pragma unroll
    for (int off = 32; off >= 1; off >>= 1) {
        psq += __shfl_xor(psq, off, 64);
        pc  += __shfl_xor(pc,  off, 64);
        ps  += __shfl_xor(ps,  off, 64);
    }
    if (lane == 0) { red[0][wave] = psq; red[1][wave] = pc; red[2][wave] = ps; }
    __syncthreads();
    if (tid == 0) {
        float sq = 0.f, sc = 0.f, ss = 0.f;
#pragma unroll
        for (int wv = 0; wv < WPB; ++wv) { sq += red[0][wv]; sc += red[1][wv]; ss += red[2][wv]; }
        const float norm = fmaxf(sqrtf(sq), 1e-12f);
        rm_sh = sc / (float)S / norm;
        im_sh = ss / (float)S / norm;
    }
    __syncthreads();
    const float rm = rm_sh, im = im_sh;

    // h1[j] = relu(rm * sum(Wo1[j,0:11]) + im * sum(Wo1[j,11:22]) + bo1[j])
    {
        float s1 = 0.0f, s2 = 0.0f;
        const float* wrow = Wo1 + tid * (2 * NQ);
#pragma unroll
        for (int k = 0; k < NQ; ++k)       s1 += wrow[k];
#pragma unroll
        for (int k = NQ; k < 2 * NQ; ++k)  s2 += wrow[k];
        h1[tid] = fmaxf(rm * s1 + im * s2 + bo1[tid], 0.0f);
    }
    __syncthreads();
    if (tid < 128) {
        float acc = bo2[tid];
        const float* wrow = Wo2 + tid * 256;
        for (int k = 0; k < 256; ++k) acc += h1[k] * wrow[k];
        h2[tid] = fmaxf(acc, 0.0f);
    }
    __syncthreads();
    if (tid < 64) {
        float acc = bo3[tid];
        const float* wrow = Wo3 + tid * 128;
        for (int k = 0; k < 128; ++k) acc += h2[k] * wrow[k];
        out[bb * 64 + tid] = acc;
    }
}

extern "C" void kernel_launch(void* const* d_in, const int* in_sizes, int n_in,
                              void* d_out, int out_size, void* d_ws, size_t ws_size,
                              hipStream_t stream) {
    const float* nf     = (const float*)d_in[0];
    // d_in[1] = edge_indices (unused by the math)
    const float* W1     = (const float*)d_in[2];
    const float* b1     = (const float*)d_in[3];
    const float* W2     = (const float*)d_in[4];
    const float* b2     = (const float*)d_in[5];
    const float* rot    = (const float*)d_in[6];
    const float* ent    = (const float*)d_in[7];
    const float* msg    = (const float*)d_in[8];
    const float* pool_w = (const float*)d_in[9];
    const float* Wo1    = (const float*)d_in[10];
    const float* bo1    = (const float*)d_in[11];
    const float* Wo2    = (const float*)d_in[12];
    const float* bo2    = (const float*)d_in[13];
    const float* Wo3    = (const float*)d_in[14];
    const float* bo3    = (const float*)d_in[15];

    float*    Rpart = (float*)d_ws;                   // [NBLK, S]
    unsigned* flags = (unsigned*)(Rpart + NBLK * S);  // [NBLK]; poison 0xAAAAAAAA != MAGIC

    fused_kernel<<<dim3(NBLK), dim3(256), 0, stream>>>(
        nf, W1, b1, W2, b2, rot, ent, msg, pool_w,
        Wo1, bo1, Wo2, bo2, Wo3, bo3, Rpart, flags, (float*)d_out);
}